// Round 3
// baseline (199.974 us; speedup 1.0000x reference)
//
#include <hip/hip_runtime.h>
#include <hip/hip_bf16.h>

// Problem constants (B,H,W,C = 32,32,32,256 -> l = 1024)
#define BATCH 32
#define L 1024
#define CD 256
#define TM 64          // pred rows per block
#define RT_PER_B 16    // L / TM row-tiles per batch
#define SP_LD (CD + 8) // bf16 leading dim: 264*2=528 B row stride, 16-B aligned

typedef __bf16 bf16x8 __attribute__((ext_vector_type(8)));
typedef __bf16 bf16x4 __attribute__((ext_vector_type(4)));
typedef float  f32x4  __attribute__((ext_vector_type(4)));

// Monotonic (order-preserving) float32 -> uint32 encoding
__device__ __forceinline__ unsigned int enc_f32(float f) {
    unsigned int u = __float_as_uint(f);
    return ((int)u < 0) ? ~u : (u | 0x80000000u);
}
__device__ __forceinline__ float dec_f32(unsigned int u) {
    u = (u & 0x80000000u) ? (u & 0x7FFFFFFFu) : ~u;
    return __uint_as_float(u);
}
__device__ __forceinline__ unsigned long long pmax(unsigned long long a, unsigned long long b) {
    return a > b ? a : b;
}

// Kernel 1: per (batch, row-tile) block. Wave layout 1x4: wave w owns cols
// [nt*64 + w*16, +16) x all 64 rows (4 stacked 16x16 MFMA tiles). A (preds)
// staged once in LDS as bf16; B (queries) loaded global->reg per nt (q read
// exactly once per block; L2-hot across the batch's 16 blocks). The nt loop
// is barrier-free: no sQ staging, no cross-wave column combine.
__global__ __launch_bounds__(256) void mm_argmax_kernel(
    const float* __restrict__ qg,   // feats1 [B][L][CD]  (queries)
    const float* __restrict__ pg,   // feats2 [B][L][CD]  (preds)
    unsigned long long* __restrict__ colpart,  // [B][RT_PER_B][L] packed (enc(val)<<32)|~a
    int* __restrict__ max2)                    // [B][L] argmax_j per pred row
{
    __shared__ __bf16 sP[TM][SP_LD];
    __shared__ unsigned long long sRowW[4][TM];

    const int tid = threadIdx.x;
    const int bid = blockIdx.x;
    // bid = rt*32 + b: under round-robin dispatch (xcd = bid%8), batch b's 16
    // rt-blocks all land on XCD b%8 -> q[b] (1 MB) stays hot in that 4 MB L2.
    const int b    = bid & 31;
    const int rt   = bid >> 5;
    const int row0 = rt * TM;

    const int lane = tid & 63;
    const int w    = tid >> 6;            // wave 0..3 -> column group
    const int quad = lane >> 4;
    const int l16  = lane & 15;

    const float* pB = pg + ((size_t)b * L + row0) * CD;
    const float* qB = qg + (size_t)b * L * CD;

    // ---- stage P tile (64 x 256) fp32 -> bf16 LDS, once ----
    {
        const int r  = tid >> 2;
        const int f0 = (tid & 3) * 16;
        const float4* src = (const float4*)(pB + r * CD) + f0;
        #pragma unroll
        for (int i = 0; i < 16; ++i) {
            float4 v = src[i];
            bf16x4 o;
            o[0] = (__bf16)v.x; o[1] = (__bf16)v.y; o[2] = (__bf16)v.z; o[3] = (__bf16)v.w;
            *(bf16x4*)&sP[r][(f0 + i) * 4] = o;
        }
    }
    __syncthreads();

    unsigned long long rowbest[4][4];
    #pragma unroll
    for (int tm = 0; tm < 4; ++tm)
        #pragma unroll
        for (int r = 0; r < 4; ++r) rowbest[tm][r] = 0ull;

    for (int nt = 0; nt < 16; ++nt) {
        const unsigned int jcol = (unsigned int)(nt * 64 + w * 16 + l16);
        const float* qlane = qB + (size_t)jcol * CD + quad * 8;

        f32x4 acc[4];
        #pragma unroll
        for (int tm = 0; tm < 4; ++tm) acc[tm] = (f32x4){0.f, 0.f, 0.f, 0.f};

        #pragma unroll
        for (int kk = 0; kk < 8; ++kk) {
            // B-frag: lane (quad,l16) needs q[jcol][kk*32 + quad*8 .. +8]
            float4 v0 = *(const float4*)(qlane + kk * 32);
            float4 v1 = *(const float4*)(qlane + kk * 32 + 4);
            bf16x8 bf;
            bf[0] = (__bf16)v0.x; bf[1] = (__bf16)v0.y; bf[2] = (__bf16)v0.z; bf[3] = (__bf16)v0.w;
            bf[4] = (__bf16)v1.x; bf[5] = (__bf16)v1.y; bf[6] = (__bf16)v1.z; bf[7] = (__bf16)v1.w;
            #pragma unroll
            for (int tm = 0; tm < 4; ++tm) {
                bf16x8 af = *(const bf16x8*)&sP[tm * 16 + l16][kk * 32 + quad * 8];
                acc[tm] = __builtin_amdgcn_mfma_f32_16x16x32_bf16(af, bf, acc[tm], 0, 0, 0);
            }
        }

        // ---- argmax epilogue (no barriers) ----
        // C/D layout: col = l16 (-> jcol), row = tm*16 + quad*4 + r
        unsigned long long cbest = 0ull;
        const unsigned long long jpk = (unsigned long long)(unsigned int)(~jcol);
        #pragma unroll
        for (int tm = 0; tm < 4; ++tm) {
            #pragma unroll
            for (int r = 0; r < 4; ++r) {
                const unsigned int e = enc_f32(acc[tm][r]);
                const unsigned int aidx = (unsigned int)(row0 + tm * 16 + quad * 4 + r);
                cbest = pmax(cbest, ((unsigned long long)e << 32) | (unsigned int)(~aidx));
                rowbest[tm][r] = pmax(rowbest[tm][r], ((unsigned long long)e << 32) | jpk);
            }
        }
        // full 64-row column max: reduce across quads only
        cbest = pmax(cbest, __shfl_xor(cbest, 16));
        cbest = pmax(cbest, __shfl_xor(cbest, 32));
        if (quad == 0)
            colpart[((size_t)b * RT_PER_B + rt) * L + jcol] = cbest;
    }

    // ---- row argmax: reduce over this wave's 16 col-lanes, then across waves ----
    #pragma unroll
    for (int tm = 0; tm < 4; ++tm) {
        #pragma unroll
        for (int r = 0; r < 4; ++r) {
            unsigned long long pk = rowbest[tm][r];
            pk = pmax(pk, __shfl_xor(pk, 1));
            pk = pmax(pk, __shfl_xor(pk, 2));
            pk = pmax(pk, __shfl_xor(pk, 4));
            pk = pmax(pk, __shfl_xor(pk, 8));
            rowbest[tm][r] = pk;
        }
    }
    if (l16 == 0) {
        #pragma unroll
        for (int tm = 0; tm < 4; ++tm)
            #pragma unroll
            for (int r = 0; r < 4; ++r)
                sRowW[w][tm * 16 + quad * 4 + r] = rowbest[tm][r];
    }
    __syncthreads();
    if (w == 0) {
        unsigned long long m = pmax(pmax(sRowW[0][lane], sRowW[1][lane]),
                                    pmax(sRowW[2][lane], sRowW[3][lane]));
        max2[(size_t)b * L + row0 + lane] = (int)(~(unsigned int)m);
    }
}

// Kernel 2: per-batch final reduction — combine colpart over row-tiles,
// mutual-NN check, masked mean. (R1-proven 256-thread shape.)
__global__ __launch_bounds__(256) void finalize_kernel(
    const unsigned long long* __restrict__ colpart,
    const int* __restrict__ max2,
    float* __restrict__ out)
{
    __shared__ int sMax2[L];
    __shared__ float sSum[4];
    __shared__ int sCnt[4];
    const int b = blockIdx.x;
    const int tid = threadIdx.x;

    for (int i = tid; i < L; i += 256) sMax2[i] = max2[(size_t)b * L + i];
    __syncthreads();

    float sum = 0.f;
    int cnt = 0;
    #pragma unroll
    for (int i = 0; i < 4; ++i) {
        const int j = tid + i * 256;
        unsigned long long best = 0ull;
        #pragma unroll
        for (int rt = 0; rt < RT_PER_B; ++rt)
            best = pmax(best, colpart[((size_t)b * RT_PER_B + rt) * L + j]);
        const int a = (int)(~(unsigned int)best) & (L - 1);    // max1[j] (clamped)
        const float val = dec_f32((unsigned int)(best >> 32)); // sims[j]
        if (sMax2[a] == j) { sum += val; ++cnt; }              // mutual NN
    }
    #pragma unroll
    for (int o = 32; o >= 1; o >>= 1) {
        sum += __shfl_down(sum, o);
        cnt += __shfl_down(cnt, o);
    }
    if ((tid & 63) == 0) { sSum[tid >> 6] = sum; sCnt[tid >> 6] = cnt; }
    __syncthreads();
    if (tid == 0) {
        float S = sSum[0] + sSum[1] + sSum[2] + sSum[3];
        int   C = sCnt[0] + sCnt[1] + sCnt[2] + sCnt[3];
        out[b] = S / fmaxf((float)C, 1.0f);
    }
}

extern "C" void kernel_launch(void* const* d_in, const int* in_sizes, int n_in,
                              void* d_out, int out_size, void* d_ws, size_t ws_size,
                              hipStream_t stream) {
    const float* q = (const float*)d_in[0];   // feats1
    const float* p = (const float*)d_in[1];   // feats2
    float* out = (float*)d_out;

    // ws layout: colpart [32][16][1024] u64 = 4 MiB, then max2 [32][1024] int = 128 KiB.
    // Every slot is written by kernel 1 before kernel 2 reads it -> no init needed.
    unsigned long long* colpart = (unsigned long long*)d_ws;
    int* max2 = (int*)((char*)d_ws + (size_t)BATCH * RT_PER_B * L * sizeof(unsigned long long));

    mm_argmax_kernel<<<BATCH * RT_PER_B, 256, 0, stream>>>(q, p, colpart, max2);
    finalize_kernel<<<BATCH, 256, 0, stream>>>(colpart, max2, out);
}

// Round 5
// 135.442 us; speedup vs baseline: 1.4765x; 1.4765x over previous
//
#include <hip/hip_runtime.h>
#include <hip/hip_bf16.h>

// Problem constants (B,H,W,C = 32,32,32,256 -> l = 1024)
#define BATCH 32
#define L 1024
#define CD 256
#define TM 64          // pred rows per block
#define TN 64          // query cols per n-tile
#define NT (L / TN)    // 16 column tiles
#define KC 128         // K half-phase staged per barrier pair (32 float4 slots)
#define RT_PER_B 16
#define SP_LD (CD + 8) // sP leading dim (bf16): 528-B row stride
#define SQ_LD (KC + 8) // sQ leading dim (bf16): 272-B row stride

typedef __bf16 bf16x8 __attribute__((ext_vector_type(8)));
typedef __bf16 bf16x4 __attribute__((ext_vector_type(4)));
typedef float  f32x4  __attribute__((ext_vector_type(4)));

__device__ __forceinline__ unsigned int enc_f32(float f) {
    unsigned int u = __float_as_uint(f);
    return ((int)u < 0) ? ~u : (u | 0x80000000u);
}
__device__ __forceinline__ float dec_f32(unsigned int u) {
    u = (u & 0x80000000u) ? (u & 0x7FFFFFFFu) : ~u;
    return __uint_as_float(u);
}
__device__ __forceinline__ unsigned long long pmax(unsigned long long a, unsigned long long b) {
    return a > b ? a : b;
}
__device__ __forceinline__ bf16x4 cvt4(float4 v) {
    bf16x4 o;
    o[0] = (__bf16)v.x; o[1] = (__bf16)v.y; o[2] = (__bf16)v.z; o[3] = (__bf16)v.w;
    return o;
}

// Kernel 1: block = (batch, 64-row tile). 2x2 waves, each 32 rows x 32 cols.
// A (preds) staged once; B (queries) staged per (nt, k-phase) through a
// register-prefetch pipeline: loads for the next phase are issued before the
// barrier, so global latency overlaps compute. Column-argmax cross-wave
// combine piggybacks on the existing barriers (no extra syncs).
__global__ __launch_bounds__(256) void mm_argmax_kernel(
    const float* __restrict__ qg,   // feats1 [B][L][CD]  (queries)
    const float* __restrict__ pg,   // feats2 [B][L][CD]  (preds)
    unsigned long long* __restrict__ colpart,  // [B][16][L] packed (enc(val)<<32)|~a
    int* __restrict__ max2)                    // [B][L] argmax_j per pred row
{
    __shared__ __bf16 sP[TM][SP_LD];          // 33792 B
    __shared__ __bf16 sQ[TN][SQ_LD];          // 17408 B
    __shared__ unsigned long long sCol[TN];   // 512 B
    __shared__ unsigned long long sRowW[2][TM];

    const int tid = threadIdx.x;
    const int bid = blockIdx.x;
    // bid = rt*32 + b: round-robin dispatch puts batch b's 16 blocks on XCD b%8
    const int b    = bid & 31;
    const int rt   = bid >> 5;
    const int row0 = rt * TM;

    const int lane = tid & 63;
    const int w    = tid >> 6;
    const int wm   = w >> 1;      // wave row: 32 rows
    const int wn   = w & 1;       // wave col: 32 cols
    const int quad = lane >> 4;
    const int l16  = lane & 15;

    const float* pB = pg + ((size_t)b * L + row0) * CD;
    const float* qB = qg + (size_t)b * L * CD;

    // ---- stage P tile (64 x 256) fp32 -> bf16 LDS, once ----
    // CD = 256 floats = 64 float4 slots per row; 4 threads/row x 16 slots.
    const int sr = tid >> 2;          // staging row 0..63
    const int sc = tid & 3;           // staging col-group 0..3
    {
        const float4* src = (const float4*)(pB + sr * CD);
        #pragma unroll
        for (int i = 0; i < 16; ++i)
            *(bf16x4*)&sP[sr][(sc + i * 4) * 4] = cvt4(src[sc + i * 4]);
    }

    // ---- prefetch first q phase (nt=0, kc=0): 64 rows x 128 k ----
    // KC = 128 floats = 32 float4 slots per row; 4 threads/row x 8 slots
    // (slot = sc + i*4, covers [0,32) exactly).
    float4 pf[8];
    {
        const float4* src = (const float4*)(qB + (size_t)sr * CD);
        #pragma unroll
        for (int i = 0; i < 8; ++i) pf[i] = src[sc + i * 4];
    }

    unsigned long long rowbest[2][4];
    #pragma unroll
    for (int tm = 0; tm < 2; ++tm)
        #pragma unroll
        for (int r = 0; r < 4; ++r) rowbest[tm][r] = 0ull;
    unsigned long long pend[2] = {0ull, 0ull};

    for (int nt = 0; nt < NT; ++nt) {
        f32x4 acc[2][2];
        #pragma unroll
        for (int tm = 0; tm < 2; ++tm)
            #pragma unroll
            for (int tn = 0; tn < 2; ++tn) acc[tm][tn] = (f32x4){0.f, 0.f, 0.f, 0.f};

        for (int kc = 0; kc < 2; ++kc) {
            if (nt || kc) __syncthreads();   // B1: prev-phase readers of sQ done
            // piggyback drain: wm=1 combines+stores tile nt-1's column partials
            // (sCol written by wm=0 before B1; wm=0's next sCol write is two
            //  barriers later -> no race)
            if (kc == 0 && nt > 0 && wm == 1 && quad == 0) {
                #pragma unroll
                for (int tn = 0; tn < 2; ++tn) {
                    const int c = wn * 32 + tn * 16 + l16;
                    colpart[((size_t)b * RT_PER_B + rt) * L + (nt - 1) * TN + c] =
                        pmax(pend[tn], sCol[c]);
                }
            }
            // stage current phase from prefetch regs
            #pragma unroll
            for (int i = 0; i < 8; ++i)
                *(bf16x4*)&sQ[sr][(sc + i * 4) * 4] = cvt4(pf[i]);
            // issue prefetch for next phase (overlaps barrier + compute)
            if (!(nt == NT - 1 && kc == 1)) {
                const int nnt = (kc == 0) ? nt : nt + 1;
                const int nkc = kc ^ 1;
                const float4* src = (const float4*)(qB + (size_t)(nnt * TN + sr) * CD + nkc * KC);
                #pragma unroll
                for (int i = 0; i < 8; ++i) pf[i] = src[sc + i * 4];
            }
            __syncthreads();                 // B2: sQ ready
            #pragma unroll
            for (int kk = 0; kk < 4; ++kk) {
                const int ka = kc * KC + kk * 32 + quad * 8;
                const int kb = kk * 32 + quad * 8;
                bf16x8 a0 = *(const bf16x8*)&sP[wm * 32 +      l16][ka];
                bf16x8 a1 = *(const bf16x8*)&sP[wm * 32 + 16 + l16][ka];
                bf16x8 b0 = *(const bf16x8*)&sQ[wn * 32 +      l16][kb];
                bf16x8 b1 = *(const bf16x8*)&sQ[wn * 32 + 16 + l16][kb];
                acc[0][0] = __builtin_amdgcn_mfma_f32_16x16x32_bf16(a0, b0, acc[0][0], 0, 0, 0);
                acc[0][1] = __builtin_amdgcn_mfma_f32_16x16x32_bf16(a0, b1, acc[0][1], 0, 0, 0);
                acc[1][0] = __builtin_amdgcn_mfma_f32_16x16x32_bf16(a1, b0, acc[1][0], 0, 0, 0);
                acc[1][1] = __builtin_amdgcn_mfma_f32_16x16x32_bf16(a1, b1, acc[1][1], 0, 0, 0);
            }
        }

        // ---- epilogue: column partials (32 rows per wave) + row running max ----
        // C/D layout: col = l16, row = tm*16 + quad*4 + r  (m89/m91 verified)
        #pragma unroll
        for (int tn = 0; tn < 2; ++tn) {
            const unsigned int jcol = (unsigned int)(nt * TN + wn * 32 + tn * 16 + l16);
            const unsigned long long jpk = (unsigned long long)(unsigned int)(~jcol);
            unsigned long long cbest = 0ull;
            #pragma unroll
            for (int tm = 0; tm < 2; ++tm) {
                #pragma unroll
                for (int r = 0; r < 4; ++r) {
                    const unsigned int e = enc_f32(acc[tm][tn][r]);
                    const unsigned int aidx =
                        (unsigned int)(row0 + wm * 32 + tm * 16 + quad * 4 + r);
                    cbest = pmax(cbest, ((unsigned long long)e << 32) | (unsigned int)(~aidx));
                    rowbest[tm][r] = pmax(rowbest[tm][r], ((unsigned long long)e << 32) | jpk);
                }
            }
            cbest = pmax(cbest, __shfl_xor(cbest, 16));
            cbest = pmax(cbest, __shfl_xor(cbest, 32));
            if (quad == 0) {
                const int c = wn * 32 + tn * 16 + l16;
                if (wm == 0) sCol[c] = cbest;
                else         pend[tn] = cbest;
            }
        }
    }

    // ---- final column drain for tile NT-1 ----
    __syncthreads();
    if (wm == 1 && quad == 0) {
        #pragma unroll
        for (int tn = 0; tn < 2; ++tn) {
            const int c = wn * 32 + tn * 16 + l16;
            colpart[((size_t)b * RT_PER_B + rt) * L + (NT - 1) * TN + c] =
                pmax(pend[tn], sCol[c]);
        }
    }

    // ---- row argmax: reduce over 16 col-lanes, combine across wn pair ----
    #pragma unroll
    for (int tm = 0; tm < 2; ++tm) {
        #pragma unroll
        for (int r = 0; r < 4; ++r) {
            unsigned long long pk = rowbest[tm][r];
            pk = pmax(pk, __shfl_xor(pk, 1));
            pk = pmax(pk, __shfl_xor(pk, 2));
            pk = pmax(pk, __shfl_xor(pk, 4));
            pk = pmax(pk, __shfl_xor(pk, 8));
            rowbest[tm][r] = pk;
        }
    }
    if (l16 == 0) {
        #pragma unroll
        for (int tm = 0; tm < 2; ++tm)
            #pragma unroll
            for (int r = 0; r < 4; ++r)
                sRowW[wn][wm * 32 + tm * 16 + quad * 4 + r] = rowbest[tm][r];
    }
    __syncthreads();
    if (w == 0) {
        unsigned long long m = pmax(sRowW[0][lane], sRowW[1][lane]);
        max2[(size_t)b * L + row0 + lane] = (int)(~(unsigned int)m);
    }
}

// Kernel 2: per-batch final reduction (R1/R3-proven shape).
__global__ __launch_bounds__(256) void finalize_kernel(
    const unsigned long long* __restrict__ colpart,
    const int* __restrict__ max2,
    float* __restrict__ out)
{
    __shared__ int sMax2[L];
    __shared__ float sSum[4];
    __shared__ int sCnt[4];
    const int b = blockIdx.x;
    const int tid = threadIdx.x;

    for (int i = tid; i < L; i += 256) sMax2[i] = max2[(size_t)b * L + i];
    __syncthreads();

    float sum = 0.f;
    int cnt = 0;
    #pragma unroll
    for (int i = 0; i < 4; ++i) {
        const int j = tid + i * 256;
        unsigned long long best = 0ull;
        #pragma unroll
        for (int rt = 0; rt < RT_PER_B; ++rt)
            best = pmax(best, colpart[((size_t)b * RT_PER_B + rt) * L + j]);
        const int a = (int)(~(unsigned int)best) & (L - 1);    // max1[j]
        const float val = dec_f32((unsigned int)(best >> 32)); // sims[j]
        if (sMax2[a] == j) { sum += val; ++cnt; }              // mutual NN
    }
    #pragma unroll
    for (int o = 32; o >= 1; o >>= 1) {
        sum += __shfl_down(sum, o);
        cnt += __shfl_down(cnt, o);
    }
    if ((tid & 63) == 0) { sSum[tid >> 6] = sum; sCnt[tid >> 6] = cnt; }
    __syncthreads();
    if (tid == 0) {
        float S = sSum[0] + sSum[1] + sSum[2] + sSum[3];
        int   C = sCnt[0] + sCnt[1] + sCnt[2] + sCnt[3];
        out[b] = S / fmaxf((float)C, 1.0f);
    }
}

extern "C" void kernel_launch(void* const* d_in, const int* in_sizes, int n_in,
                              void* d_out, int out_size, void* d_ws, size_t ws_size,
                              hipStream_t stream) {
    const float* q = (const float*)d_in[0];   // feats1
    const float* p = (const float*)d_in[1];   // feats2
    float* out = (float*)d_out;

    // ws layout: colpart [32][16][1024] u64 = 4 MiB, then max2 [32][1024] int.
    // Every slot written by kernel 1 before kernel 2 reads it -> no init needed.
    unsigned long long* colpart = (unsigned long long*)d_ws;
    int* max2 = (int*)((char*)d_ws + (size_t)BATCH * RT_PER_B * L * sizeof(unsigned long long));

    mm_argmax_kernel<<<BATCH * RT_PER_B, 256, 0, stream>>>(q, p, colpart, max2);
    finalize_kernel<<<BATCH, 256, 0, stream>>>(colpart, max2, out);
}